// Round 4
// baseline (621.941 us; speedup 1.0000x reference)
//
#include <hip/hip_runtime.h>
#include <hip/hip_bf16.h>
#include <cmath>

#define T_STEPS 16
#define BATCH   512
#define N_IN    3072
#define S1      256
#define S2      256
#define S3      128
#define NEXP    8
#define M_ROWS  (T_STEPS * BATCH)   // 8192
#define MT_ALL  (M_ROWS / 32)       // 256 m-tiles

typedef int v4i  __attribute__((ext_vector_type(4)));
typedef int v16i __attribute__((ext_vector_type(16)));
typedef unsigned long long u64;
typedef unsigned int uint32;

// ---------------------------------------------------------------------------
// bit->byte unpack: 16 bits -> 16 i8 (0/1). mul-free: 2x v_lshl_add_u32 per
// word (v_mul_lo_u32 is quarter-rate; 16 of them/body was ~18% of R3's wall).
// ---------------------------------------------------------------------------
__device__ __forceinline__ v4i unpack16_bits(uint32 w16)
{
    v4i d;
    #pragma unroll
    for (int c = 0; c < 4; ++c) {
        uint32 x = (w16 >> (4 * c)) & 0xFu;
        x = x + (x << 7);          // bits 0..3 -> 0..3,7..10
        x = x + (x << 14);         // -> 0..3,7..10,14..17,21..24
        d[c] = (int)(x & 0x01010101u);
    }
    return d;
}

// ---------------------------------------------------------------------------
// Weight digitize -> MFMA fragment tiles. B-row gr = o*32 + e*4 + limb.
// Bf[kb][nt=o][lane16][16], lane16 = (e*4+limb) + 32*qd, k = kb*32+qd*16+byte.
// ---------------------------------------------------------------------------
template<int S, int K>
__device__ __forceinline__ void digitize_chunk(
    const float* __restrict__ W, char* __restrict__ Bf, int t)
{
    int lane16 = t & 63;
    int o  = (t >> 6) & (S - 1);
    int kb = t >> ((S == 256) ? 14 : 13);
    int r  = lane16 & 31;
    int qd = lane16 >> 5;
    int e    = r >> 2;
    int limb = r & 3;
    int k0 = kb * 32 + qd * 16;

    const float4* Wp = (const float4*)(W + ((size_t)e * S + o) * K + k0);
    char out[16];
    #pragma unroll
    for (int f4 = 0; f4 < 4; ++f4) {
        float4 w = Wp[f4];
        float ws[4] = {w.x, w.y, w.z, w.w};
        #pragma unroll
        for (int c = 0; c < 4; ++c) {
            long long q = llrint((double)ws[c] * 4294967296.0);
            int d = 0;
            #pragma unroll
            for (int l = 0; l < 4; ++l) {
                int dl = (int)((q + 128) & 255) - 128;
                q = (q - dl) >> 8;
                if (l == limb) d = dl;
            }
            out[f4 * 4 + c] = (char)d;
        }
    }
    *(v4i*)(Bf + (size_t)t * 16) = *(v4i*)out;
}

// ---------------------------------------------------------------------------
// Single prep dispatch = pack_x_bits + digitize W1/W2/W3.
// ---------------------------------------------------------------------------
__global__ __launch_bounds__(256) void prep(
    const float* __restrict__ x,  const float* __restrict__ W1,
    const float* __restrict__ W2, const float* __restrict__ W3,
    u64* __restrict__ bitsT, char* __restrict__ B1f,
    char* __restrict__ B2f,  char* __restrict__ B3f)
{
    const int bid = blockIdx.x;
    const int tid = threadIdx.x;
    if (bid < 98304) {
        int gid = bid * 256 + tid;
        float v = x[gid];
        u64 m = __ballot(v >= 0.5f);
        if ((tid & 63) == 0) {
            int tb = gid / N_IN;                 // t*512 + b
            int k  = gid - tb * N_IN;
            int t  = tb >> 9;
            int b  = tb & 511;
            bitsT[(size_t)(k >> 6) * M_ROWS + (b * 16 + t)] = m;
        }
    } else if (bid < 98304 + 6144) {
        digitize_chunk<S1, N_IN>(W1, B1f, (bid - 98304) * 256 + tid);
    } else if (bid < 98304 + 6144 + 512) {
        digitize_chunk<S2, S1>(W2, B2f, (bid - 98304 - 6144) * 256 + tid);
    } else {
        digitize_chunk<S3, S2>(W3, B3f, (bid - 98304 - 6656) * 256 + tid);
    }
}

// ---------------------------------------------------------------------------
// Fused expert-GEMM + limb recombine + LIF + gated combine + mean.
// R13 geometry is parametric: wave tile WM x WN, 4 waves stacked in m
// (block = 4*WM m-rows x WN B-rows; all waves share B -> L1 dedup).
//   stage 1 (ABITS): WM=32, WN=128 -> unpack/MFMA halves vs R3 (2 unpack
//     calls feed 8 MFMA), acc stays 64 regs. NS=8 keeps per-XCD B slab at
//     3 MB < 4 MB L2 (R2's failure was a 6 MB slab).
//   stages 2/3 (frag): WM=64, WN=64 -> R3's proven shape (no unpack there).
// Clamp-free distance-1 prefetch into padded buffers. No setprio (suspected
// interleave fighter, m190; R3 showed no gain from it).
// 1-D grid, XCD swizzle: xcd = id&7 owns one n-slab -> B L2-resident.
// ---------------------------------------------------------------------------
template<int K, int S, int SHIFT, bool ABITS, bool WRITEC,
         int WM, int WN, int NBLK, int MINW>
__global__ __launch_bounds__(256, MINW) void fused_stage(
    const void* __restrict__ Ap, const char* __restrict__ Bf,
    const float* __restrict__ g, char* __restrict__ Cf,
    float* __restrict__ Mean)
{
    constexpr int KI  = K / 64;
    static_assert(KI % 2 == 0, "KI must be even");
    constexpr int MTW = WM / 32;             // m-tiles per wave
    constexpr int NTW = WN / 32;             // n-tiles per wave
    constexpr int BM  = 4 * WM;              // block m-rows
    constexpr int NT  = S;                   // 32-row n-tiles in Bf (S*32 rows)
    constexpr int NS  = NBLK / 8;
    __shared__ double hs[BM][8 * NTW];       // 32 KB in both geometries

    const int tid  = threadIdx.x;
    const int lane = tid & 63;
    const int w    = tid >> 6;
    const int col  = lane & 31;
    const int qd   = lane >> 5;
    const int wm   = w * WM;

    // XCD-swizzled block mapping: id = mblk*NBLK + inner*8 + xcd
    const int id   = blockIdx.x;
    const int nblk = (id & 7) * NS + ((id >> 3) % NS);
    const int mblk = id / NBLK;
    const int m0   = mblk * BM;

    const int nt0 = nblk * NTW;
    const char* Bbase = Bf + ((size_t)nt0 * 64 + lane) * 16;

    v16i acc[MTW][NTW];
    #pragma unroll
    for (int i = 0; i < MTW; ++i)
        #pragma unroll
        for (int j = 0; j < NTW; ++j)
            #pragma unroll
            for (int r = 0; r < 16; ++r) acc[i][j][r] = 0;

    auto loadB = [&](int kb, int jj) -> v4i {
        return *(const v4i*)(Bbase + (size_t)kb * (NT * 1024) + jj * 1024);
    };

    v4i Bb[2][2 * NTW];

    if constexpr (ABITS) {
        // transposed bits: AT[it][m'], contiguous in m'
        const u64* AT = (const u64*)Ap + (m0 + wm + col);
        const int sh16 = qd * 16;
        u64 ab[2][MTW];

        // preload body 0
        #pragma unroll
        for (int mt = 0; mt < MTW; ++mt) ab[0][mt] = AT[mt * 32];
        #pragma unroll
        for (int ks = 0; ks < 2; ++ks)
            #pragma unroll
            for (int jj = 0; jj < NTW; ++jj)
                Bb[0][ks * NTW + jj] = loadB(ks, jj);

        // no clamp: body it prefetches it+1 unconditionally (buffers padded)
        auto body = [&](int it, int cur, int pf) {
            const int itp = it + 1;
            #pragma unroll
            for (int mt = 0; mt < MTW; ++mt)
                ab[pf][mt] = AT[(size_t)itp * M_ROWS + mt * 32];
            #pragma unroll
            for (int ks = 0; ks < 2; ++ks)
                #pragma unroll
                for (int jj = 0; jj < NTW; ++jj)
                    Bb[pf][ks * NTW + jj] = loadB(itp * 2 + ks, jj);
            #pragma unroll
            for (int ks = 0; ks < 2; ++ks) {
                v4i af[MTW];
                #pragma unroll
                for (int mt = 0; mt < MTW; ++mt) {
                    uint32 dw = ks ? (uint32)(ab[cur][mt] >> 32)
                                   : (uint32)ab[cur][mt];
                    af[mt] = unpack16_bits(dw >> sh16);
                }
                #pragma unroll
                for (int mt = 0; mt < MTW; ++mt)
                    #pragma unroll
                    for (int jj = 0; jj < NTW; ++jj)
                        acc[mt][jj] = __builtin_amdgcn_mfma_i32_32x32x32_i8(
                            af[mt], Bb[cur][ks * NTW + jj], acc[mt][jj], 0,0,0);
            }
        };
        for (int it = 0; it < KI; it += 2) {
            body(it + 0, 0, 1);
            body(it + 1, 1, 0);
        }
    } else {
        // A in fragment-tile layout: Af[kb][mt][lane][16]
        const int mt0 = (m0 + wm) >> 5;
        const char* Abase = (const char*)Ap + ((size_t)mt0 * 64 + lane) * 16;
        auto loadA = [&](int kb, int ii) -> v4i {
            return *(const v4i*)(Abase + (size_t)kb * (MT_ALL * 1024) + ii * 1024);
        };
        v4i Ab[2][2 * MTW];

        // preload body 0
        #pragma unroll
        for (int ks = 0; ks < 2; ++ks) {
            #pragma unroll
            for (int mt = 0; mt < MTW; ++mt)
                Ab[0][ks * MTW + mt] = loadA(ks, mt);
            #pragma unroll
            for (int jj = 0; jj < NTW; ++jj)
                Bb[0][ks * NTW + jj] = loadB(ks, jj);
        }

        auto body = [&](int it, int cur, int pf) {
            const int itp = it + 1;
            #pragma unroll
            for (int ks = 0; ks < 2; ++ks) {
                #pragma unroll
                for (int mt = 0; mt < MTW; ++mt)
                    Ab[pf][ks * MTW + mt] = loadA(itp * 2 + ks, mt);
                #pragma unroll
                for (int jj = 0; jj < NTW; ++jj)
                    Bb[pf][ks * NTW + jj] = loadB(itp * 2 + ks, jj);
            }
            #pragma unroll
            for (int ks = 0; ks < 2; ++ks)
                #pragma unroll
                for (int mt = 0; mt < MTW; ++mt)
                    #pragma unroll
                    for (int jj = 0; jj < NTW; ++jj)
                        acc[mt][jj] = __builtin_amdgcn_mfma_i32_32x32x32_i8(
                            Ab[cur][ks * MTW + mt], Bb[cur][ks * NTW + jj],
                            acc[mt][jj], 0,0,0);
        };
        for (int it = 0; it < KI; it += 2) {
            body(it + 0, 0, 1);
            body(it + 1, 1, 0);
        }
    }

    // ---- limb recombine (exact): int pair-combine then one f64 fma ----
    // lanes col&3 = limb. s01 = l0 + 256*l1 (|l|<2^19 -> fits i32 exactly);
    // s23 from xor-2 partner; d = (s01 + 65536*s23) * 2^-SHIFT, exact in f64.
    const double sbase = 1.0 / (double)(1ll << SHIFT);
    #pragma unroll
    for (int j = 0; j < NTW; ++j) {
        const int oe = j * 8 + (col >> 2);            // o_loc*8 + e
        #pragma unroll
        for (int i = 0; i < MTW; ++i) {
            #pragma unroll
            for (int reg = 0; reg < 16; ++reg) {
                int a = acc[i][j][reg];
                int s01 = a + (__shfl_xor(a, 1) << 8);
                int s23 = __shfl_xor(s01, 2);
                double d = ((double)s01 + 65536.0 * (double)s23) * sbase;
                if ((col & 3) == 0) {
                    int m = wm + i * 32 + (reg & 3) + 8 * (reg >> 2) + 4 * qd;
                    hs[m][oe] = d;
                }
            }
        }
    }
    __syncthreads();

    // ---- LIF scan: 256 threads = (b_loc, o_loc in [0,NTW), e in [0,8)) ----
    const int b_loc  = tid >> (3 + (NTW == 2 ? 1 : 2));
    const int o_loc  = (tid >> 3) & (NTW - 1);
    const int e      = tid & 7;
    const int oe     = o_loc * 8 + e;
    const float ge   = g[e];
    const int bg = mblk * (BM / 16) + b_loc;
    const int og = nblk * NTW + o_loc;

    // fragment-tile write coords for counts (k = og of this stage)
    const int kb_a   = og >> 5;
    const int qd_a   = (og >> 4) & 1;
    const int byte_a = og & 15;

    double v = 0.0;
    float gacc = 0.0f;
    #pragma unroll
    for (int t = 0; t < T_STEPS; ++t) {
        double h  = hs[b_loc * 16 + t][oe];
        double vv = v * 0.95 + h;
        int spk = (vv >= 1.0) ? 1 : 0;
        v = vv - (double)spk;
        float gs = ge * (float)spk;
        gs += __shfl_xor(gs, 1);
        gs += __shfl_xor(gs, 2);
        gs += __shfl_xor(gs, 4);
        gacc += gs;
        if (WRITEC) {
            int cnt = spk;
            cnt += __shfl_xor(cnt, 1);
            cnt += __shfl_xor(cnt, 2);
            cnt += __shfl_xor(cnt, 4);
            if (e == 0) {
                int mp = bg * 16 + t;
                int lane_a = (mp & 31) + 32 * qd_a;
                Cf[(((size_t)kb_a * MT_ALL + (mp >> 5)) * 64 + lane_a) * 16 + byte_a]
                    = (char)cnt;
            }
        }
    }
    if (e == 0) Mean[(size_t)bg * S + og] = gacc * 0.0625f;
}

// ---------------------------------------------------------------------------
// ws layout (bytes), all buffers padded for clamp-free distance-1 prefetch:
//   AbitsT @ 0          : 3 MB + 64 KB pad
//   B1f    @ 4194304    : 24 MB + 512 KB pad
//   B2f    @ 31457280   :  2 MB + 512 KB pad
//   B3f    @ 34603008   :  1 MB + 256 KB pad
//   c1f    @ 36175872   :  2 MB + 512 KB pad
//   c2f    @ 39321600   :  2 MB + 512 KB pad   -> end 41943040 (40 MB)
// ---------------------------------------------------------------------------
extern "C" void kernel_launch(void* const* d_in, const int* in_sizes, int n_in,
                              void* d_out, int out_size, void* d_ws, size_t ws_size,
                              hipStream_t stream) {
    const float* x  = (const float*)d_in[0];
    const float* W1 = (const float*)d_in[1];
    const float* W2 = (const float*)d_in[2];
    const float* W3 = (const float*)d_in[3];
    const float* g1 = (const float*)d_in[4];
    const float* g2 = (const float*)d_in[5];
    const float* g3 = (const float*)d_in[6];
    float* out = (float*)d_out;

    char* ws = (char*)d_ws;
    u64*  AbitsT = (u64*)ws;
    char* B1f    = ws + 4194304ull;
    char* B2f    = ws + 31457280ull;
    char* B3f    = ws + 34603008ull;
    char* c1f    = ws + 36175872ull;
    char* c2f    = ws + 39321600ull;

    dim3 blk(256);

    // --- single precompute dispatch ---
    prep<<<98304 + 6144 + 512 + 256, blk, 0, stream>>>(
        x, W1, W2, W3, AbitsT, B1f, B2f, B3f);

    // --- three fused GEMM+LIF stages, XCD-swizzled 1-D grids ---
    // stage 1: block 128m x 128n -> mblk=64, nblk=64 (NS=8: 3 MB B/XCD)
    fused_stage<N_IN, S1, 32, true,  true,  32, 128, 64, 3>
        <<<64 * 64, blk, 0, stream>>>(AbitsT, B1f, g1, c1f, out);
    // stage 2: block 256m x 64n -> mblk=32, nblk=128 (R3 shape)
    fused_stage<S1,   S2, 35, false, true,  64, 64, 128, 3>
        <<<32 * 128, blk, 0, stream>>>(c1f, B2f, g2, c2f, out + BATCH * S1);
    // stage 3: block 256m x 64n -> mblk=32, nblk=64
    fused_stage<S2,   S3, 35, false, false, 64, 64, 64, 3>
        <<<32 * 64, blk, 0, stream>>>(c2f, B3f, g3, nullptr, out + BATCH * (S1 + S2));
}

// Round 5
// 540.276 us; speedup vs baseline: 1.1512x; 1.1512x over previous
//
#include <hip/hip_runtime.h>
#include <hip/hip_bf16.h>
#include <cmath>

#define T_STEPS 16
#define BATCH   512
#define N_IN    3072
#define S1      256
#define S2      256
#define S3      128
#define NEXP    8
#define M_ROWS  (T_STEPS * BATCH)   // 8192
#define MT_ALL  (M_ROWS / 32)       // 256 m-tiles

typedef int v4i  __attribute__((ext_vector_type(4)));
typedef int v16i __attribute__((ext_vector_type(16)));
typedef unsigned long long u64;
typedef unsigned int uint32;

// ---------------------------------------------------------------------------
// bit->byte unpack: 16 bits -> 16 i8 (0/1). mul-free (R4-proven): the old
// v_mul_lo_u32 form was 16 quarter-rate muls/body (~128 cy); this is
// 2x v_lshl_add_u32 per word ((1+2^7)(1+2^14) == 0x204081 for x<16).
// ---------------------------------------------------------------------------
__device__ __forceinline__ v4i unpack16_bits(uint32 w16)
{
    v4i d;
    #pragma unroll
    for (int c = 0; c < 4; ++c) {
        uint32 x = (w16 >> (4 * c)) & 0xFu;
        x = x + (x << 7);
        x = x + (x << 14);
        d[c] = (int)(x & 0x01010101u);
    }
    return d;
}

// ---------------------------------------------------------------------------
// Weight digitize -> MFMA fragment tiles. B-row gr = o*32 + e*4 + limb.
// Bf[kb][nt=o][lane16][16], lane16 = (e*4+limb) + 32*qd, k = kb*32+qd*16+byte.
// ---------------------------------------------------------------------------
template<int S, int K>
__device__ __forceinline__ void digitize_chunk(
    const float* __restrict__ W, char* __restrict__ Bf, int t)
{
    int lane16 = t & 63;
    int o  = (t >> 6) & (S - 1);
    int kb = t >> ((S == 256) ? 14 : 13);
    int r  = lane16 & 31;
    int qd = lane16 >> 5;
    int e    = r >> 2;
    int limb = r & 3;
    int k0 = kb * 32 + qd * 16;

    const float4* Wp = (const float4*)(W + ((size_t)e * S + o) * K + k0);
    char out[16];
    #pragma unroll
    for (int f4 = 0; f4 < 4; ++f4) {
        float4 w = Wp[f4];
        float ws[4] = {w.x, w.y, w.z, w.w};
        #pragma unroll
        for (int c = 0; c < 4; ++c) {
            long long q = llrint((double)ws[c] * 4294967296.0);
            int d = 0;
            #pragma unroll
            for (int l = 0; l < 4; ++l) {
                int dl = (int)((q + 128) & 255) - 128;
                q = (q - dl) >> 8;
                if (l == limb) d = dl;
            }
            out[f4 * 4 + c] = (char)d;
        }
    }
    *(v4i*)(Bf + (size_t)t * 16) = *(v4i*)out;
}

// ---------------------------------------------------------------------------
// Single prep dispatch = pack_x_bits + digitize W1/W2/W3.
// ---------------------------------------------------------------------------
__global__ __launch_bounds__(256) void prep(
    const float* __restrict__ x,  const float* __restrict__ W1,
    const float* __restrict__ W2, const float* __restrict__ W3,
    u64* __restrict__ bitsT, char* __restrict__ B1f,
    char* __restrict__ B2f,  char* __restrict__ B3f)
{
    const int bid = blockIdx.x;
    const int tid = threadIdx.x;
    if (bid < 98304) {
        int gid = bid * 256 + tid;
        float v = x[gid];
        u64 m = __ballot(v >= 0.5f);
        if ((tid & 63) == 0) {
            int tb = gid / N_IN;                 // t*512 + b
            int k  = gid - tb * N_IN;
            int t  = tb >> 9;
            int b  = tb & 511;
            bitsT[(size_t)(k >> 6) * M_ROWS + (b * 16 + t)] = m;
        }
    } else if (bid < 98304 + 6144) {
        digitize_chunk<S1, N_IN>(W1, B1f, (bid - 98304) * 256 + tid);
    } else if (bid < 98304 + 6144 + 512) {
        digitize_chunk<S2, S1>(W2, B2f, (bid - 98304 - 6144) * 256 + tid);
    } else {
        digitize_chunk<S3, S2>(W3, B3f, (bid - 98304 - 6656) * 256 + tid);
    }
}

// ---------------------------------------------------------------------------
// Fused expert-GEMM + limb recombine + LIF + gated combine + mean.
// R14 = R3's proven geometry (block 256m x 64n, wave tile 64x64, 8 MFMA/body;
// at this shape issue is saturated: MFMA 42 + VALU 54 = 96%) with exactly two
// deltas: mul-free unpack (cuts ~130 VALU-cy from the ~716-cy body) and no
// setprio. R4 proved the geometry must NOT change: halving in-loop VALU via
// a wider n-tile removed the latency cover and went latency-bound (25+22%).
// Clamp-free distance-1 prefetch into padded buffers; 4 waves/SIMD target.
// 1-D grid, XCD swizzle: xcd = id&7 owns one n-slab -> B L2-resident.
// ---------------------------------------------------------------------------
template<int K, int S, int SHIFT, bool ABITS, bool WRITEC, int NBLK, int MINW>
__global__ __launch_bounds__(256, MINW) void fused_stage(
    const void* __restrict__ Ap, const char* __restrict__ Bf,
    const float* __restrict__ g, char* __restrict__ Cf,
    float* __restrict__ Mean)
{
    constexpr int KI = K / 64;
    static_assert(KI % 2 == 0, "KI must be even");
    constexpr int NT = S;                    // 32-row n-tiles in Bf
    constexpr int NS = NBLK / 8;
    __shared__ double hs[256][16];           // 32 KB

    const int tid  = threadIdx.x;
    const int lane = tid & 63;
    const int w    = tid >> 6;
    const int col  = lane & 31;
    const int qd   = lane >> 5;
    const int wm   = w * 64;

    // XCD-swizzled block mapping: id = mblk*NBLK + inner*8 + xcd
    const int id   = blockIdx.x;
    const int nblk = (id & 7) * NS + ((id >> 3) % NS);
    const int mblk = id / NBLK;
    const int m0   = mblk * 256;

    const int nt0 = nblk * 2;
    const char* Bbase = Bf + ((size_t)nt0 * 64 + lane) * 16;

    v16i acc[2][2];
    #pragma unroll
    for (int i = 0; i < 2; ++i)
        #pragma unroll
        for (int j = 0; j < 2; ++j)
            #pragma unroll
            for (int r = 0; r < 16; ++r) acc[i][j][r] = 0;

    auto loadB = [&](int kb, int jj) -> v4i {
        return *(const v4i*)(Bbase + (size_t)kb * (NT * 1024) + jj * 1024);
    };

    v4i Bb[2][4];

    if constexpr (ABITS) {
        // transposed bits: AT[it][m'], contiguous in m'
        const u64* AT = (const u64*)Ap + (m0 + wm + col);
        const int sh16 = qd * 16;
        u64 a0b[2], a1b[2];

        // preload body 0
        a0b[0] = AT[0];
        a1b[0] = AT[32];
        #pragma unroll
        for (int ks = 0; ks < 2; ++ks)
            #pragma unroll
            for (int jj = 0; jj < 2; ++jj)
                Bb[0][ks * 2 + jj] = loadB(ks, jj);

        // no clamp: body it prefetches it+1 unconditionally (buffers padded)
        auto body = [&](int it, int cur, int pf) {
            const int itp = it + 1;
            a0b[pf] = AT[(size_t)itp * M_ROWS];
            a1b[pf] = AT[(size_t)itp * M_ROWS + 32];
            #pragma unroll
            for (int ks = 0; ks < 2; ++ks)
                #pragma unroll
                for (int jj = 0; jj < 2; ++jj)
                    Bb[pf][ks * 2 + jj] = loadB(itp * 2 + ks, jj);
            #pragma unroll
            for (int ks = 0; ks < 2; ++ks) {
                uint32 dw0 = ks ? (uint32)(a0b[cur] >> 32) : (uint32)a0b[cur];
                uint32 dw1 = ks ? (uint32)(a1b[cur] >> 32) : (uint32)a1b[cur];
                v4i af0 = unpack16_bits(dw0 >> sh16);
                v4i af1 = unpack16_bits(dw1 >> sh16);
                #pragma unroll
                for (int jj = 0; jj < 2; ++jj) {
                    acc[0][jj] = __builtin_amdgcn_mfma_i32_32x32x32_i8(af0, Bb[cur][ks*2+jj], acc[0][jj], 0,0,0);
                    acc[1][jj] = __builtin_amdgcn_mfma_i32_32x32x32_i8(af1, Bb[cur][ks*2+jj], acc[1][jj], 0,0,0);
                }
            }
        };
        for (int it = 0; it < KI; it += 2) {
            body(it + 0, 0, 1);
            body(it + 1, 1, 0);
        }
    } else {
        // A in fragment-tile layout: Af[kb][mt][lane][16]
        const int mt0 = (m0 + wm) >> 5;
        const char* Abase = (const char*)Ap + ((size_t)mt0 * 64 + lane) * 16;
        auto loadA = [&](int kb, int ii) -> v4i {
            return *(const v4i*)(Abase + (size_t)kb * (MT_ALL * 1024) + ii * 1024);
        };
        v4i Ab[2][4];

        // preload body 0
        #pragma unroll
        for (int ks = 0; ks < 2; ++ks) {
            Ab[0][ks * 2 + 0] = loadA(ks, 0);
            Ab[0][ks * 2 + 1] = loadA(ks, 1);
            #pragma unroll
            for (int jj = 0; jj < 2; ++jj)
                Bb[0][ks * 2 + jj] = loadB(ks, jj);
        }

        auto body = [&](int it, int cur, int pf) {
            const int itp = it + 1;
            #pragma unroll
            for (int ks = 0; ks < 2; ++ks) {
                Ab[pf][ks * 2 + 0] = loadA(itp * 2 + ks, 0);
                Ab[pf][ks * 2 + 1] = loadA(itp * 2 + ks, 1);
                #pragma unroll
                for (int jj = 0; jj < 2; ++jj)
                    Bb[pf][ks * 2 + jj] = loadB(itp * 2 + ks, jj);
            }
            #pragma unroll
            for (int ks = 0; ks < 2; ++ks)
                #pragma unroll
                for (int jj = 0; jj < 2; ++jj) {
                    acc[0][jj] = __builtin_amdgcn_mfma_i32_32x32x32_i8(Ab[cur][ks*2+0], Bb[cur][ks*2+jj], acc[0][jj], 0,0,0);
                    acc[1][jj] = __builtin_amdgcn_mfma_i32_32x32x32_i8(Ab[cur][ks*2+1], Bb[cur][ks*2+jj], acc[1][jj], 0,0,0);
                }
        };
        for (int it = 0; it < KI; it += 2) {
            body(it + 0, 0, 1);
            body(it + 1, 1, 0);
        }
    }

    // ---- limb recombine (exact): int pair-combine then one f64 fma ----
    // lanes col&3 = limb. s01 = l0 + 256*l1 (|l|<2^19 -> fits i32 exactly);
    // s23 from xor-2 partner; d = (s01 + 65536*s23) * 2^-SHIFT, exact in f64.
    const double sbase = 1.0 / (double)(1ll << SHIFT);
    #pragma unroll
    for (int j = 0; j < 2; ++j) {
        const int oe = j * 8 + (col >> 2);            // o_loc*8 + e
        #pragma unroll
        for (int i = 0; i < 2; ++i) {
            #pragma unroll
            for (int reg = 0; reg < 16; ++reg) {
                int a = acc[i][j][reg];
                int s01 = a + (__shfl_xor(a, 1) << 8);
                int s23 = __shfl_xor(s01, 2);
                double d = ((double)s01 + 65536.0 * (double)s23) * sbase;
                if ((col & 3) == 0) {
                    int m = wm + i * 32 + (reg & 3) + 8 * (reg >> 2) + 4 * qd;
                    hs[m][oe] = d;
                }
            }
        }
    }
    __syncthreads();

    // ---- LIF scan: thread = (b_loc = tid>>4, o_loc = (tid>>3)&1, e = tid&7)
    const int b_loc  = tid >> 4;
    const int o_loc  = (tid >> 3) & 1;
    const int e      = tid & 7;
    const int oe     = o_loc * 8 + e;
    const float ge   = g[e];
    const int bg = mblk * 16 + b_loc;
    const int og = nblk * 2 + o_loc;

    // fragment-tile write coords for counts (k = og of this stage)
    const int kb_a   = og >> 5;
    const int qd_a   = (og >> 4) & 1;
    const int byte_a = og & 15;

    double v = 0.0;
    float gacc = 0.0f;
    #pragma unroll
    for (int t = 0; t < T_STEPS; ++t) {
        double h  = hs[b_loc * 16 + t][oe];
        double vv = v * 0.95 + h;
        int spk = (vv >= 1.0) ? 1 : 0;
        v = vv - (double)spk;
        float gs = ge * (float)spk;
        gs += __shfl_xor(gs, 1);
        gs += __shfl_xor(gs, 2);
        gs += __shfl_xor(gs, 4);
        gacc += gs;
        if (WRITEC) {
            int cnt = spk;
            cnt += __shfl_xor(cnt, 1);
            cnt += __shfl_xor(cnt, 2);
            cnt += __shfl_xor(cnt, 4);
            if (e == 0) {
                int mp = bg * 16 + t;
                int lane_a = (mp & 31) + 32 * qd_a;
                Cf[(((size_t)kb_a * MT_ALL + (mp >> 5)) * 64 + lane_a) * 16 + byte_a]
                    = (char)cnt;
            }
        }
    }
    if (e == 0) Mean[(size_t)bg * S + og] = gacc * 0.0625f;
}

// ---------------------------------------------------------------------------
// ws layout (bytes), all buffers padded for clamp-free distance-1 prefetch:
//   AbitsT @ 0          : 3 MB + 64 KB pad
//   B1f    @ 4194304    : 24 MB + 512 KB pad
//   B2f    @ 31457280   :  2 MB + 512 KB pad
//   B3f    @ 34603008   :  1 MB + 256 KB pad
//   c1f    @ 36175872   :  2 MB + 512 KB pad
//   c2f    @ 39321600   :  2 MB + 512 KB pad   -> end 41943040 (40 MB)
// ---------------------------------------------------------------------------
extern "C" void kernel_launch(void* const* d_in, const int* in_sizes, int n_in,
                              void* d_out, int out_size, void* d_ws, size_t ws_size,
                              hipStream_t stream) {
    const float* x  = (const float*)d_in[0];
    const float* W1 = (const float*)d_in[1];
    const float* W2 = (const float*)d_in[2];
    const float* W3 = (const float*)d_in[3];
    const float* g1 = (const float*)d_in[4];
    const float* g2 = (const float*)d_in[5];
    const float* g3 = (const float*)d_in[6];
    float* out = (float*)d_out;

    char* ws = (char*)d_ws;
    u64*  AbitsT = (u64*)ws;
    char* B1f    = ws + 4194304ull;
    char* B2f    = ws + 31457280ull;
    char* B3f    = ws + 34603008ull;
    char* c1f    = ws + 36175872ull;
    char* c2f    = ws + 39321600ull;

    dim3 blk(256);

    // --- single precompute dispatch ---
    prep<<<98304 + 6144 + 512 + 256, blk, 0, stream>>>(
        x, W1, W2, W3, AbitsT, B1f, B2f, B3f);

    // --- three fused GEMM+LIF stages, XCD-swizzled 1-D grids ---
    // grids: mblk = 8192/256 = 32; nblk = (S*32)/64
    fused_stage<N_IN, S1, 32, true,  true,  128, 4><<<32 * 128, blk, 0, stream>>>(
        AbitsT, B1f, g1, c1f, out);
    fused_stage<S1,   S2, 35, false, true,  128, 3><<<32 * 128, blk, 0, stream>>>(
        c1f, B2f, g2, c2f, out + BATCH * S1);
    fused_stage<S2,   S3, 35, false, false, 64, 3><<<32 * 64, blk, 0, stream>>>(
        c2f, B3f, g3, nullptr, out + BATCH * (S1 + S2));
}

// Round 6
// 514.054 us; speedup vs baseline: 1.2099x; 1.0510x over previous
//
#include <hip/hip_runtime.h>
#include <hip/hip_bf16.h>
#include <cmath>

#define T_STEPS 16
#define BATCH   512
#define N_IN    3072
#define S1      256
#define S2      256
#define S3      128
#define NEXP    8
#define M_ROWS  (T_STEPS * BATCH)   // 8192
#define MT_ALL  (M_ROWS / 32)       // 256 m-tiles

typedef int v4i  __attribute__((ext_vector_type(4)));
typedef int v16i __attribute__((ext_vector_type(16)));
typedef unsigned long long u64;
typedef unsigned int uint32;

// ---------------------------------------------------------------------------
// bit->byte unpack: 16 bits -> 16 i8 (0/1). mul-free: 2x v_lshl_add_u32 per
// word ((1+2^7)(1+2^14) == 0x204081 for x<16). Cheaper than v_mul_lo_u32
// (quarter-rate) -- but R4/R5 proved the VALU here is ALSO latency cover:
// only shave it with prefetch-depth/setprio cover in place (R6).
// ---------------------------------------------------------------------------
__device__ __forceinline__ v4i unpack16_bits(uint32 w16)
{
    v4i d;
    #pragma unroll
    for (int c = 0; c < 4; ++c) {
        uint32 x = (w16 >> (4 * c)) & 0xFu;
        x = x + (x << 7);
        x = x + (x << 14);
        d[c] = (int)(x & 0x01010101u);
    }
    return d;
}

// ---------------------------------------------------------------------------
// Weight digitize -> MFMA fragment tiles. B-row gr = o*32 + e*4 + limb.
// Bf[kb][nt=o][lane16][16], lane16 = (e*4+limb) + 32*qd, k = kb*32+qd*16+byte.
// ---------------------------------------------------------------------------
template<int S, int K>
__device__ __forceinline__ void digitize_chunk(
    const float* __restrict__ W, char* __restrict__ Bf, int t)
{
    int lane16 = t & 63;
    int o  = (t >> 6) & (S - 1);
    int kb = t >> ((S == 256) ? 14 : 13);
    int r  = lane16 & 31;
    int qd = lane16 >> 5;
    int e    = r >> 2;
    int limb = r & 3;
    int k0 = kb * 32 + qd * 16;

    const float4* Wp = (const float4*)(W + ((size_t)e * S + o) * K + k0);
    char out[16];
    #pragma unroll
    for (int f4 = 0; f4 < 4; ++f4) {
        float4 w = Wp[f4];
        float ws[4] = {w.x, w.y, w.z, w.w};
        #pragma unroll
        for (int c = 0; c < 4; ++c) {
            long long q = llrint((double)ws[c] * 4294967296.0);
            int d = 0;
            #pragma unroll
            for (int l = 0; l < 4; ++l) {
                int dl = (int)((q + 128) & 255) - 128;
                q = (q - dl) >> 8;
                if (l == limb) d = dl;
            }
            out[f4 * 4 + c] = (char)d;
        }
    }
    *(v4i*)(Bf + (size_t)t * 16) = *(v4i*)out;
}

// ---------------------------------------------------------------------------
// Single prep dispatch = pack_x_bits + digitize W1/W2/W3.
// ---------------------------------------------------------------------------
__global__ __launch_bounds__(256) void prep(
    const float* __restrict__ x,  const float* __restrict__ W1,
    const float* __restrict__ W2, const float* __restrict__ W3,
    u64* __restrict__ bitsT, char* __restrict__ B1f,
    char* __restrict__ B2f,  char* __restrict__ B3f)
{
    const int bid = blockIdx.x;
    const int tid = threadIdx.x;
    if (bid < 98304) {
        int gid = bid * 256 + tid;
        float v = x[gid];
        u64 m = __ballot(v >= 0.5f);
        if ((tid & 63) == 0) {
            int tb = gid / N_IN;                 // t*512 + b
            int k  = gid - tb * N_IN;
            int t  = tb >> 9;
            int b  = tb & 511;
            bitsT[(size_t)(k >> 6) * M_ROWS + (b * 16 + t)] = m;
        }
    } else if (bid < 98304 + 6144) {
        digitize_chunk<S1, N_IN>(W1, B1f, (bid - 98304) * 256 + tid);
    } else if (bid < 98304 + 6144 + 512) {
        digitize_chunk<S2, S1>(W2, B2f, (bid - 98304 - 6144) * 256 + tid);
    } else {
        digitize_chunk<S3, S2>(W3, B3f, (bid - 98304 - 6656) * 256 + tid);
    }
}

// ---------------------------------------------------------------------------
// Fused expert-GEMM + limb recombine + LIF + gated combine + mean.
// R6 = consolidation of every proven-good piece at the proven 64x64 wave
// geometry (block 256m x 64n, 8 MFMA/body):
//  - distance-2 triple-buffer prefetch (R0: the deep-cover config, 224us)
//  - setprio(1) around unpack+MFMA cluster, ABITS only (R3's cover, 229us)
//  - mul-free unpack (R5-proven cheaper; R4/R5 proved it needs cover)
//  - mblk-major XCD ordering: co-resident blocks on a CU/XCD share ONE
//    B slab -> B dedups in L1 across blocks; active B per XCD-L2 768KB.
// R4/R2 bracketed the geometry: wider n-tiles go latency-bound. Don't.
// ---------------------------------------------------------------------------
template<int K, int S, int SHIFT, bool ABITS, bool WRITEC, int NBLK, int MINW>
__global__ __launch_bounds__(256, MINW) void fused_stage(
    const void* __restrict__ Ap, const char* __restrict__ Bf,
    const float* __restrict__ g, char* __restrict__ Cf,
    float* __restrict__ Mean)
{
    constexpr int KI = K / 64;
    constexpr int NT = S;                    // 32-row n-tiles in Bf
    constexpr int NS = NBLK / 8;
    static_assert(M_ROWS / 256 == 32, "mblk count must be 32");
    __shared__ double hs[256][16];           // 32 KB

    const int tid  = threadIdx.x;
    const int lane = tid & 63;
    const int w    = tid >> 6;
    const int col  = lane & 31;
    const int qd   = lane >> 5;
    const int wm   = w * 64;

    // mblk-major XCD mapping: xcd owns NS nblks; within an XCD consecutive
    // inner ids sweep all 32 mblks of ONE nblk before moving to the next ->
    // co-resident blocks share the same B slab (L1/L2 dedup). Shift-only.
    const int id    = blockIdx.x;
    const int xcd   = id & 7;
    const int inner = id >> 3;
    const int nblk  = xcd * NS + (inner >> 5);
    const int mblk  = inner & 31;
    const int m0    = mblk * 256;

    const int nt0 = nblk * 2;
    const char* Bbase = Bf + ((size_t)nt0 * 64 + lane) * 16;

    v16i acc[2][2];
    #pragma unroll
    for (int i = 0; i < 2; ++i)
        #pragma unroll
        for (int j = 0; j < 2; ++j)
            #pragma unroll
            for (int r = 0; r < 16; ++r) acc[i][j][r] = 0;

    auto loadB = [&](int kb, int jj) -> v4i {
        return *(const v4i*)(Bbase + (size_t)kb * (NT * 1024) + jj * 1024);
    };

    if constexpr (ABITS) {
        static_assert(!ABITS || KI % 3 == 0, "bits path wants KI % 3 == 0");
        // transposed bits: AT[it][m'], contiguous in m'
        const u64* AT = (const u64*)Ap + (m0 + wm + col);
        const int sh16 = qd * 16;
        u64 a0b[3], a1b[3];
        v4i Bb[3][4];

        // preload bodies 0,1 (distance-2)
        #pragma unroll
        for (int s = 0; s < 2; ++s) {
            a0b[s] = AT[(size_t)s * M_ROWS];
            a1b[s] = AT[(size_t)s * M_ROWS + 32];
            #pragma unroll
            for (int ks = 0; ks < 2; ++ks)
                #pragma unroll
                for (int jj = 0; jj < 2; ++jj)
                    Bb[s][ks * 2 + jj] = loadB(s * 2 + ks, jj);
        }

        // clamp-free: body it prefetches it+2 unconditionally (padded bufs)
        auto body = [&](int it, int cur, int pf) {
            const int itp = it + 2;
            a0b[pf] = AT[(size_t)itp * M_ROWS];
            a1b[pf] = AT[(size_t)itp * M_ROWS + 32];
            #pragma unroll
            for (int ks = 0; ks < 2; ++ks)
                #pragma unroll
                for (int jj = 0; jj < 2; ++jj)
                    Bb[pf][ks * 2 + jj] = loadB(itp * 2 + ks, jj);
            __builtin_amdgcn_s_setprio(1);
            #pragma unroll
            for (int ks = 0; ks < 2; ++ks) {
                uint32 dw0 = ks ? (uint32)(a0b[cur] >> 32) : (uint32)a0b[cur];
                uint32 dw1 = ks ? (uint32)(a1b[cur] >> 32) : (uint32)a1b[cur];
                v4i af0 = unpack16_bits(dw0 >> sh16);
                v4i af1 = unpack16_bits(dw1 >> sh16);
                #pragma unroll
                for (int jj = 0; jj < 2; ++jj) {
                    acc[0][jj] = __builtin_amdgcn_mfma_i32_32x32x32_i8(af0, Bb[cur][ks*2+jj], acc[0][jj], 0,0,0);
                    acc[1][jj] = __builtin_amdgcn_mfma_i32_32x32x32_i8(af1, Bb[cur][ks*2+jj], acc[1][jj], 0,0,0);
                }
            }
            __builtin_amdgcn_s_setprio(0);
        };
        for (int it = 0; it < KI; it += 3) {
            body(it + 0, 0, 2);
            body(it + 1, 1, 0);
            body(it + 2, 2, 1);
        }
    } else {
        static_assert(ABITS || KI % 2 == 0, "frag path wants even KI");
        // A in fragment-tile layout: Af[kb][mt][lane][16]
        const int mt0 = (m0 + wm) >> 5;
        const char* Abase = (const char*)Ap + ((size_t)mt0 * 64 + lane) * 16;
        auto loadA = [&](int kb, int ii) -> v4i {
            return *(const v4i*)(Abase + (size_t)kb * (MT_ALL * 1024) + ii * 1024);
        };
        v4i Ab[2][4];
        v4i Bb[2][4];

        // preload body 0
        #pragma unroll
        for (int ks = 0; ks < 2; ++ks) {
            Ab[0][ks * 2 + 0] = loadA(ks, 0);
            Ab[0][ks * 2 + 1] = loadA(ks, 1);
            #pragma unroll
            for (int jj = 0; jj < 2; ++jj)
                Bb[0][ks * 2 + jj] = loadB(ks, jj);
        }

        auto body = [&](int it, int cur, int pf) {
            const int itp = it + 1;
            #pragma unroll
            for (int ks = 0; ks < 2; ++ks) {
                Ab[pf][ks * 2 + 0] = loadA(itp * 2 + ks, 0);
                Ab[pf][ks * 2 + 1] = loadA(itp * 2 + ks, 1);
                #pragma unroll
                for (int jj = 0; jj < 2; ++jj)
                    Bb[pf][ks * 2 + jj] = loadB(itp * 2 + ks, jj);
            }
            #pragma unroll
            for (int ks = 0; ks < 2; ++ks)
                #pragma unroll
                for (int jj = 0; jj < 2; ++jj) {
                    acc[0][jj] = __builtin_amdgcn_mfma_i32_32x32x32_i8(Ab[cur][ks*2+0], Bb[cur][ks*2+jj], acc[0][jj], 0,0,0);
                    acc[1][jj] = __builtin_amdgcn_mfma_i32_32x32x32_i8(Ab[cur][ks*2+1], Bb[cur][ks*2+jj], acc[1][jj], 0,0,0);
                }
        };
        for (int it = 0; it < KI; it += 2) {
            body(it + 0, 0, 1);
            body(it + 1, 1, 0);
        }
    }

    // ---- limb recombine (exact): int pair-combine then one f64 fma ----
    // lanes col&3 = limb. s01 = l0 + 256*l1 (|l|<2^19 -> fits i32 exactly);
    // s23 from xor-2 partner; d = (s01 + 65536*s23) * 2^-SHIFT, exact in f64.
    const double sbase = 1.0 / (double)(1ll << SHIFT);
    #pragma unroll
    for (int j = 0; j < 2; ++j) {
        const int oe = j * 8 + (col >> 2);            // o_loc*8 + e
        #pragma unroll
        for (int i = 0; i < 2; ++i) {
            #pragma unroll
            for (int reg = 0; reg < 16; ++reg) {
                int a = acc[i][j][reg];
                int s01 = a + (__shfl_xor(a, 1) << 8);
                int s23 = __shfl_xor(s01, 2);
                double d = ((double)s01 + 65536.0 * (double)s23) * sbase;
                if ((col & 3) == 0) {
                    int m = wm + i * 32 + (reg & 3) + 8 * (reg >> 2) + 4 * qd;
                    hs[m][oe] = d;
                }
            }
        }
    }
    __syncthreads();

    // ---- LIF scan: thread = (b_loc = tid>>4, o_loc = (tid>>3)&1, e = tid&7)
    const int b_loc  = tid >> 4;
    const int o_loc  = (tid >> 3) & 1;
    const int e      = tid & 7;
    const int oe     = o_loc * 8 + e;
    const float ge   = g[e];
    const int bg = mblk * 16 + b_loc;
    const int og = nblk * 2 + o_loc;

    // fragment-tile write coords for counts (k = og of this stage)
    const int kb_a   = og >> 5;
    const int qd_a   = (og >> 4) & 1;
    const int byte_a = og & 15;

    double v = 0.0;
    float gacc = 0.0f;
    #pragma unroll
    for (int t = 0; t < T_STEPS; ++t) {
        double h  = hs[b_loc * 16 + t][oe];
        double vv = v * 0.95 + h;
        int spk = (vv >= 1.0) ? 1 : 0;
        v = vv - (double)spk;
        float gs = ge * (float)spk;
        gs += __shfl_xor(gs, 1);
        gs += __shfl_xor(gs, 2);
        gs += __shfl_xor(gs, 4);
        gacc += gs;
        if (WRITEC) {
            int cnt = spk;
            cnt += __shfl_xor(cnt, 1);
            cnt += __shfl_xor(cnt, 2);
            cnt += __shfl_xor(cnt, 4);
            if (e == 0) {
                int mp = bg * 16 + t;
                int lane_a = (mp & 31) + 32 * qd_a;
                Cf[(((size_t)kb_a * MT_ALL + (mp >> 5)) * 64 + lane_a) * 16 + byte_a]
                    = (char)cnt;
            }
        }
    }
    if (e == 0) Mean[(size_t)bg * S + og] = gacc * 0.0625f;
}

// ---------------------------------------------------------------------------
// ws layout (bytes), buffers padded for clamp-free distance-2 prefetch:
//   AbitsT @ 0          : 3 MB + up to 1 MB pad (A prefetch to word KI+1)
//   B1f    @ 4194304    : 24 MB + ~2 MB pad (kb up to 2*KI+3 < region end)
//   B2f    @ 31457280   :  2 MB + 512 KB pad
//   B3f    @ 34603008   :  1 MB + 256 KB pad
//   c1f    @ 36175872   :  2 MB + 512 KB pad
//   c2f    @ 39321600   :  2 MB + 512 KB pad   -> end 41943040 (40 MB)
// ---------------------------------------------------------------------------
extern "C" void kernel_launch(void* const* d_in, const int* in_sizes, int n_in,
                              void* d_out, int out_size, void* d_ws, size_t ws_size,
                              hipStream_t stream) {
    const float* x  = (const float*)d_in[0];
    const float* W1 = (const float*)d_in[1];
    const float* W2 = (const float*)d_in[2];
    const float* W3 = (const float*)d_in[3];
    const float* g1 = (const float*)d_in[4];
    const float* g2 = (const float*)d_in[5];
    const float* g3 = (const float*)d_in[6];
    float* out = (float*)d_out;

    char* ws = (char*)d_ws;
    u64*  AbitsT = (u64*)ws;
    char* B1f    = ws + 4194304ull;
    char* B2f    = ws + 31457280ull;
    char* B3f    = ws + 34603008ull;
    char* c1f    = ws + 36175872ull;
    char* c2f    = ws + 39321600ull;

    dim3 blk(256);

    // --- single precompute dispatch ---
    prep<<<98304 + 6144 + 512 + 256, blk, 0, stream>>>(
        x, W1, W2, W3, AbitsT, B1f, B2f, B3f);

    // --- three fused GEMM+LIF stages, mblk-major XCD-swizzled 1-D grids ---
    // grids: 8 xcd * NS nblk * 32 mblk
    fused_stage<N_IN, S1, 32, true,  true,  128, 3><<<32 * 128, blk, 0, stream>>>(
        AbitsT, B1f, g1, c1f, out);
    fused_stage<S1,   S2, 35, false, true,  128, 3><<<32 * 128, blk, 0, stream>>>(
        c1f, B2f, g2, c2f, out + BATCH * S1);
    fused_stage<S2,   S3, 35, false, false, 64, 3><<<32 * 64, blk, 0, stream>>>(
        c2f, B3f, g3, nullptr, out + BATCH * (S1 + S2));
}